// Round 5
// baseline (34.896 us; speedup 1.0000x reference)
//
#include <hip/hip_runtime.h>
#include <math.h>

#define B_ 128
#define N_ 16800
#define CHUNK_ 4200          // anchors per chunk (4 chunks per row)
#define CHUNK4_ 1050         // uint4 units per chunk
#define NCHUNK 4
#define NBLK_A (B_ * NCHUNK) // 512 blocks = 2 per CU
#define NBINS 2048           // linear bins over [0,8), width 1/256
#define BINSCALE 256.0f
#define FLT_EPS_ 1.1920929e-7f

__device__ __forceinline__ float bce_of(float x, float y) {
    return fmaxf(x, 0.f) - x * y + __logf(1.f + __expf(-fabsf(x)));
}
__device__ __forceinline__ unsigned int bin_of(float v) {
    unsigned int b = (unsigned int)(v * BINSCALE);
    return b > (NBINS - 1u) ? (NBINS - 1u) : b;
}

// ---------- Kernel A: pure-streaming dense pass + compacted positives ----------
__global__ __launch_bounds__(1024) void pass1_kernel(
    const float* __restrict__ pbboxs,
    const float* __restrict__ plabels,
    const float* __restrict__ gbboxs,
    const float* __restrict__ glabels,
    const float* __restrict__ ancs,
    unsigned int* __restrict__ g_hc,   // [NBLK_A][NBINS] counts
    float*        __restrict__ g_hs,   // [NBLK_A][NBINS] value sums
    float* __restrict__ g_lb,          // [NBLK_A]
    float* __restrict__ g_pbce,        // [NBLK_A]
    int*   __restrict__ g_pn)          // [NBLK_A]
{
    __shared__ unsigned int s_hc[NBINS];     // 8 KB
    __shared__ float        s_hs[NBINS];     // 8 KB
    __shared__ int          s_posn[CHUNK_];  // 16.8 KB (worst case all positive)
    __shared__ unsigned int s_pcnt;
    __shared__ float s_rf[16], s_rf2[16];

    const int tid  = threadIdx.x;
    const int lane = tid & 63;
    const int wave = tid >> 6;
    const int b    = blockIdx.x >> 2;
    const int h    = blockIdx.x & 3;

    if (tid == 0) s_pcnt = 0u;
    s_hc[tid] = 0u; s_hc[tid + 1024] = 0u;
    s_hs[tid] = 0.f; s_hs[tid + 1024] = 0.f;
    __syncthreads();

    const uint4* pl4 = (const uint4*)(plabels + (size_t)b * N_) + h * CHUNK4_;
    const uint4* gl4 = (const uint4*)(glabels + (size_t)b * N_) + h * CHUNK4_;

    float acc_pbce = 0.f;

    // ---- dense phase: streaming only, no scattered loads ----
    for (int i = tid; i < CHUNK4_; i += 1024) {
        uint4 xu = pl4[i];
        uint4 yu = gl4[i];
        unsigned int xb[4] = {xu.x, xu.y, xu.z, xu.w};
        unsigned int yb[4] = {yu.x, yu.y, yu.z, yu.w};
        #pragma unroll
        for (int j = 0; j < 4; ++j) {
            float x = __uint_as_float(xb[j]);
            float y = __uint_as_float(yb[j]);
            float bce = bce_of(x, y);
            bool  pos = (y > 0.f);
            float lneg = pos ? 0.f : bce;
            unsigned int bb = bin_of(lneg);
            atomicAdd(&s_hc[bb], 1u);
            atomicAdd(&s_hs[bb], lneg);
            if (pos) {
                acc_pbce += bce;
                unsigned int idx = atomicAdd(&s_pcnt, 1u);
                s_posn[idx] = (h * CHUNK4_ + i) * 4 + j;
            }
        }
    }
    __syncthreads();   // hist + positive list complete

    // ---- hist write-out first (fire-and-forget, overlaps positive phase) ----
    if (tid < 512) {
        ((uint4*)(g_hc + (size_t)blockIdx.x * NBINS))[tid] = ((const uint4*)s_hc)[tid];
    } else {
        ((float4*)(g_hs + (size_t)blockIdx.x * NBINS))[tid - 512] =
            ((const float4*)s_hs)[tid - 512];
    }

    // ---- positive phase: all scattered loads issued in parallel ----
    const int pcnt = (int)s_pcnt;
    const float4* p4 = (const float4*)(pbboxs + (size_t)b * N_ * 4);
    const float4* g4 = (const float4*)(gbboxs + (size_t)b * N_ * 4);
    const float4* a4 = (const float4*)ancs;

    float acc_lb = 0.f;
    for (int i = tid; i < pcnt; i += 1024) {
        int n = s_posn[i];
        float4 p = p4[n], g = g4[n], a = a4[n];
        float d0 = p.x - 10.f * __fdividef(g.x - a.x, a.z);
        float d1 = p.y - 10.f * __fdividef(g.y - a.y, a.w);
        float d2 = p.z - 5.f * __logf(__fdividef(g.z, a.z));
        float d3 = p.w - 5.f * __logf(__fdividef(g.w, a.w));
        float a0 = fabsf(d0), a1 = fabsf(d1), a2 = fabsf(d2), a3 = fabsf(d3);
        acc_lb += ((a0 < 1.f) ? 0.5f * d0 * d0 : a0 - 0.5f)
                + ((a1 < 1.f) ? 0.5f * d1 * d1 : a1 - 0.5f)
                + ((a2 < 1.f) ? 0.5f * d2 * d2 : a2 - 0.5f)
                + ((a3 < 1.f) ? 0.5f * d3 * d3 : a3 - 0.5f);
    }

    // ---- block reduce lb + pbce ----
    #pragma unroll
    for (int off = 32; off > 0; off >>= 1) {
        acc_lb   += __shfl_xor(acc_lb, off);
        acc_pbce += __shfl_xor(acc_pbce, off);
    }
    if (lane == 0) { s_rf[wave] = acc_lb; s_rf2[wave] = acc_pbce; }
    __syncthreads();
    if (tid == 0) {
        float t1 = 0.f, t2 = 0.f;
        for (int w = 0; w < 16; ++w) { t1 += s_rf[w]; t2 += s_rf2[w]; }
        g_lb[blockIdx.x]   = t1;
        g_pbce[blockIdx.x] = t2;
        g_pn[blockIdx.x]   = pcnt;
    }
}

// ---------- Kernel B: per-row select from hists + fused final mean ----------
__global__ __launch_bounds__(1024) void select_final_kernel(
    const unsigned int* __restrict__ g_hc,
    const float* __restrict__ g_hs,
    const float* __restrict__ g_lb,
    const float* __restrict__ g_pbce,
    const int*   __restrict__ g_pn,
    float*        __restrict__ g_rowc,   // [3][B_]
    unsigned int* __restrict__ g_cnt,    // zeroed each call
    float*        __restrict__ out)
{
    __shared__ unsigned int s_wtot[16];
    __shared__ float s_rf[16];
    __shared__ unsigned int s_sel[2];
    __shared__ float s_tavg;
    __shared__ int s_last;

    const int tid  = threadIdx.x;
    const int lane = tid & 63;
    const int wave = tid >> 6;
    const int b    = blockIdx.x;

    const int pn = g_pn[4*b] + g_pn[4*b+1] + g_pn[4*b+2] + g_pn[4*b+3];
    int k = 3 * pn; if (k > N_) k = N_;

    float sum_sel = 0.f;   // meaningful on tid 0

    if (k > 0) {           // block-uniform branch
        // thread t owns bins {2t, 2t+1}; merge 4 chunk hists
        unsigned int c0 = 0u, c1 = 0u;
        float s0 = 0.f, s1 = 0.f;
        #pragma unroll
        for (int ch = 0; ch < NCHUNK; ++ch) {
            uint2  cu = ((const uint2*)(g_hc + (size_t)(b * NCHUNK + ch) * NBINS))[tid];
            float2 su = ((const float2*)(g_hs + (size_t)(b * NCHUNK + ch) * NBINS))[tid];
            c0 += cu.x; c1 += cu.y;
            s0 += su.x; s1 += su.y;
        }
        unsigned int pc = c0 + c1;

        // inclusive suffix scan (higher tid = higher bins)
        unsigned int suf = pc;
        #pragma unroll
        for (int off = 1; off < 64; off <<= 1) {
            unsigned int o = __shfl_down(suf, off);
            if (lane + off < 64) suf += o;
        }
        if (lane == 0) s_wtot[wave] = suf;
        __syncthreads();
        unsigned int above = 0u;
        for (int w = wave + 1; w < 16; ++w) above += s_wtot[w];
        unsigned int r = suf + above;    // suffix from bin 2t

        unsigned int scur = r; r -= c0;
        if (scur >= (unsigned int)k && r < (unsigned int)k) {
            s_sel[0] = (unsigned int)(2 * tid);
            s_sel[1] = (unsigned int)k - r;
            s_tavg   = s0 / (float)c0;
        }
        scur = r; r -= c1;
        if (scur >= (unsigned int)k && r < (unsigned int)k) {
            s_sel[0] = (unsigned int)(2 * tid + 1);
            s_sel[1] = (unsigned int)k - r;
            s_tavg   = s1 / (float)c1;
        }
        __syncthreads();
        const unsigned int b1 = s_sel[0], remk = s_sel[1];

        float sg = 0.f;
        if ((unsigned int)(2 * tid)     > b1) sg += s0;
        if ((unsigned int)(2 * tid + 1) > b1) sg += s1;
        #pragma unroll
        for (int off = 32; off > 0; off >>= 1) sg += __shfl_xor(sg, off);
        if (lane == 0) s_rf[wave] = sg;
        __syncthreads();
        if (tid == 0) {
            float t = 0.f;
            for (int w = 0; w < 16; ++w) t += s_rf[w];
            sum_sel = t + (float)remk * s_tavg;
        }
    }

    // ---- per-row contribution + last-block final mean ----
    if (tid == 0) {
        float row_lb = g_lb[4*b] + g_lb[4*b+1] + g_lb[4*b+2] + g_lb[4*b+3];
        float row_pb = g_pbce[4*b] + g_pbce[4*b+1] + g_pbce[4*b+2] + g_pbce[4*b+3];
        float nm  = (pn > 0) ? 1.f : 0.f;
        float pcn = fmaxf((float)pn, FLT_EPS_);
        g_rowc[b]          = row_lb * nm / pcn;
        g_rowc[B_ + b]     = (row_pb + sum_sel) * nm / pcn;
        g_rowc[2 * B_ + b] = nm / pcn;
        __threadfence();
        unsigned int old = atomicAdd(g_cnt, 1u);
        s_last = (old == (unsigned int)(B_ - 1)) ? 1 : 0;
    }
    __syncthreads();
    if (s_last && wave == 0) {
        // atomic reads bypass stale L1/L2 lines; fixed tree -> deterministic
        float lb_t = atomicAdd(&g_rowc[lane], 0.f)          + atomicAdd(&g_rowc[lane + 64], 0.f);
        float ll_t = atomicAdd(&g_rowc[B_ + lane], 0.f)     + atomicAdd(&g_rowc[B_ + lane + 64], 0.f);
        float w_t  = atomicAdd(&g_rowc[2 * B_ + lane], 0.f) + atomicAdd(&g_rowc[2 * B_ + lane + 64], 0.f);
        #pragma unroll
        for (int off = 32; off > 0; off >>= 1) {
            lb_t += __shfl_xor(lb_t, off);
            ll_t += __shfl_xor(ll_t, off);
            w_t  += __shfl_xor(w_t, off);
        }
        if (lane == 0) {
            float LB = lb_t * (1.f / B_);
            float LL = ll_t * (1.f / B_);
            float W  = w_t  * (1.f / B_);
            out[0] = (LB + LL) * W;
            out[1] = LB;
            out[2] = LL;
        }
    }
}

extern "C" void kernel_launch(void* const* d_in, const int* in_sizes, int n_in,
                              void* d_out, int out_size, void* d_ws, size_t ws_size,
                              hipStream_t stream) {
    const float* pbboxs  = (const float*)d_in[0];
    const float* plabels = (const float*)d_in[1];
    const float* gbboxs  = (const float*)d_in[2];
    const float* glabels = (const float*)d_in[3];
    const float* ancs    = (const float*)d_in[4];
    float* out = (float*)d_out;

    char* ws = (char*)d_ws;
    unsigned int* g_cnt = (unsigned int*)ws;                             // 4 B (+pad 64)
    unsigned int* g_hc  = (unsigned int*)(ws + 64);                      // 4 MB
    float* g_hs = (float*)(ws + 64 + (size_t)NBLK_A * NBINS * 4);        // 4 MB
    size_t off = 64 + (size_t)NBLK_A * NBINS * 8;
    float* g_lb   = (float*)(ws + off);  off += NBLK_A * 4;
    float* g_pbce = (float*)(ws + off);  off += NBLK_A * 4;
    int*   g_pn   = (int*)(ws + off);    off += NBLK_A * 4;
    float* g_rowc = (float*)(ws + off);

    hipMemsetAsync(g_cnt, 0, 4, stream);   // arrival counter only

    pass1_kernel<<<NBLK_A, 1024, 0, stream>>>(
        pbboxs, plabels, gbboxs, glabels, ancs, g_hc, g_hs, g_lb, g_pbce, g_pn);
    select_final_kernel<<<B_, 1024, 0, stream>>>(
        g_hc, g_hs, g_lb, g_pbce, g_pn, g_rowc, g_cnt, out);
}

// Round 6
// 25.739 us; speedup vs baseline: 1.3557x; 1.3557x over previous
//
#include <hip/hip_runtime.h>
#include <math.h>

#define B_ 128
#define N_ 16800
#define CHUNK4_ 1050         // uint4 units per chunk (4 chunks per row)
#define NCHUNK 4
#define NBLK_A (B_ * NCHUNK) // 512 blocks = 2 per CU
#define NBINS 2048           // linear bins over [0,8), width 1/256
#define BINSCALE 256.0f
#define FIXSCALE 1048576.0f  // 2^20 fixed-point for packed bin sums
#define INV_FIX (1.0f / 1048576.0f)
#define FLT_EPS_ 1.1920929e-7f

__device__ __forceinline__ float bce_of(float x, float y) {
    return fmaxf(x, 0.f) - x * y + __logf(1.f + __expf(-fabsf(x)));
}
__device__ __forceinline__ unsigned int bin_of(float v) {
    unsigned int b = (unsigned int)(v * BINSCALE);
    return b > (NBINS - 1u) ? (NBINS - 1u) : b;
}

// ---------- Kernel A: streaming pass, 512 blocks, single packed-u64 hist ----------
__global__ __launch_bounds__(1024) void pass1_kernel(
    const float* __restrict__ pbboxs,
    const float* __restrict__ plabels,
    const float* __restrict__ gbboxs,
    const float* __restrict__ glabels,
    const float* __restrict__ ancs,
    unsigned long long* __restrict__ g_h,   // [NBLK_A][NBINS] packed (sum<<24 | count)
    float* __restrict__ g_lb,               // [NBLK_A]
    float* __restrict__ g_pbce,             // [NBLK_A]
    int*   __restrict__ g_pn,               // [NBLK_A]
    unsigned int* __restrict__ g_cnt)       // arrival counter for kernel B
{
    __shared__ unsigned long long s_h[NBINS];   // 16 KB
    __shared__ float s_rf[16], s_rf2[16];
    __shared__ int   s_ri[16];

    const int tid  = threadIdx.x;
    const int lane = tid & 63;
    const int wave = tid >> 6;
    const int b    = blockIdx.x >> 2;
    const int h    = blockIdx.x & 3;

    s_h[tid] = 0ull; s_h[tid + 1024] = 0ull;
    if (blockIdx.x == 0 && tid == 0) *g_cnt = 0u;   // visible to kernel B via stream order
    __syncthreads();

    const uint4*  pl4 = (const uint4*)(plabels + (size_t)b * N_) + h * CHUNK4_;
    const uint4*  gl4 = (const uint4*)(glabels + (size_t)b * N_) + h * CHUNK4_;
    const float4* p4  = (const float4*)(pbboxs + (size_t)b * N_ * 4);
    const float4* g4  = (const float4*)(gbboxs + (size_t)b * N_ * 4);
    const float4* a4  = (const float4*)ancs;

    float acc_lb = 0.f, acc_pbce = 0.f;
    int   acc_pn = 0;

    // dense loop: one uint4-pair per thread (1050/1024 -> 1-2 iterations)
    for (int i = tid; i < CHUNK4_; i += 1024) {
        uint4 xu = pl4[i];
        uint4 yu = gl4[i];
        unsigned int xb[4] = {xu.x, xu.y, xu.z, xu.w};
        unsigned int yb[4] = {yu.x, yu.y, yu.z, yu.w};
        #pragma unroll
        for (int j = 0; j < 4; ++j) {
            float x = __uint_as_float(xb[j]);
            float y = __uint_as_float(yb[j]);
            float bce = bce_of(x, y);
            bool  pos = (y > 0.f);
            float lneg = pos ? 0.f : bce;
            unsigned long long pk =
                ((unsigned long long)(unsigned int)(lneg * FIXSCALE) << 24) | 1ull;
            atomicAdd(&s_h[bin_of(lneg)], pk);
            if (pos) {
                acc_pbce += bce;
                acc_pn   += 1;
                int n = (h * CHUNK4_ + i) * 4 + j;
                float4 p = p4[n], g = g4[n], a = a4[n];
                float d0 = p.x - 10.f * __fdividef(g.x - a.x, a.z);
                float d1 = p.y - 10.f * __fdividef(g.y - a.y, a.w);
                float d2 = p.z - 5.f * __logf(__fdividef(g.z, a.z));
                float d3 = p.w - 5.f * __logf(__fdividef(g.w, a.w));
                float a0 = fabsf(d0), a1 = fabsf(d1), a2 = fabsf(d2), a3 = fabsf(d3);
                acc_lb += ((a0 < 1.f) ? 0.5f * d0 * d0 : a0 - 0.5f)
                        + ((a1 < 1.f) ? 0.5f * d1 * d1 : a1 - 0.5f)
                        + ((a2 < 1.f) ? 0.5f * d2 * d2 : a2 - 0.5f)
                        + ((a3 < 1.f) ? 0.5f * d3 * d3 : a3 - 0.5f);
            }
        }
    }
    __syncthreads();

    // hist write-out: 2048 u64 = 1024 uint4, one per thread, coalesced
    ((uint4*)(g_h + (size_t)blockIdx.x * NBINS))[tid] = ((const uint4*)s_h)[tid];

    #pragma unroll
    for (int off = 32; off > 0; off >>= 1) {
        acc_lb   += __shfl_xor(acc_lb, off);
        acc_pbce += __shfl_xor(acc_pbce, off);
        acc_pn   += __shfl_xor(acc_pn, off);
    }
    if (lane == 0) { s_rf[wave] = acc_lb; s_rf2[wave] = acc_pbce; s_ri[wave] = acc_pn; }
    __syncthreads();
    if (tid == 0) {
        float t1 = 0.f, t2 = 0.f; int t3 = 0;
        for (int w = 0; w < 16; ++w) { t1 += s_rf[w]; t2 += s_rf2[w]; t3 += s_ri[w]; }
        g_lb[blockIdx.x] = t1; g_pbce[blockIdx.x] = t2; g_pn[blockIdx.x] = t3;
    }
}

// ---------- Kernel B: per-row select from packed hists + fused final mean ----------
__global__ __launch_bounds__(1024) void select_final_kernel(
    const unsigned long long* __restrict__ g_h,
    const float* __restrict__ g_lb,
    const float* __restrict__ g_pbce,
    const int*   __restrict__ g_pn,
    float*        __restrict__ g_rowc,   // [3][B_]
    unsigned int* __restrict__ g_cnt,    // zeroed by pass1
    float*        __restrict__ out)
{
    __shared__ unsigned int s_wtot[16];
    __shared__ float s_rf[16];
    __shared__ unsigned int s_sel[2];
    __shared__ float s_tavg;
    __shared__ int s_last;

    const int tid  = threadIdx.x;
    const int lane = tid & 63;
    const int wave = tid >> 6;
    const int b    = blockIdx.x;

    const int pn = g_pn[4*b] + g_pn[4*b+1] + g_pn[4*b+2] + g_pn[4*b+3];
    int k = 3 * pn; if (k > N_) k = N_;

    float sum_sel = 0.f;   // meaningful on tid 0

    if (k > 0) {           // block-uniform branch
        // thread t owns bins {2t, 2t+1}; merge 4 chunk hists (packed adds are safe:
        // total count 16800 < 2^24, no carry into sum field)
        unsigned long long h0 = 0ull, h1 = 0ull;
        #pragma unroll
        for (int ch = 0; ch < NCHUNK; ++ch) {
            const uint4 u = ((const uint4*)(g_h + (size_t)(b * NCHUNK + ch) * NBINS))[tid];
            h0 += ((unsigned long long)u.y << 32) | u.x;
            h1 += ((unsigned long long)u.w << 32) | u.z;
        }
        const unsigned int c0 = (unsigned int)(h0 & 0xFFFFFFull);
        const unsigned int c1 = (unsigned int)(h1 & 0xFFFFFFull);
        const float s0 = (float)(h0 >> 24) * INV_FIX;
        const float s1 = (float)(h1 >> 24) * INV_FIX;
        unsigned int pc = c0 + c1;

        // inclusive suffix scan (higher tid = higher bins)
        unsigned int suf = pc;
        #pragma unroll
        for (int off = 1; off < 64; off <<= 1) {
            unsigned int o = __shfl_down(suf, off);
            if (lane + off < 64) suf += o;
        }
        if (lane == 0) s_wtot[wave] = suf;
        __syncthreads();
        unsigned int above = 0u;
        for (int w = wave + 1; w < 16; ++w) above += s_wtot[w];
        unsigned int r = suf + above;    // suffix count from bin 2t

        unsigned int scur = r; r -= c0;
        if (scur >= (unsigned int)k && r < (unsigned int)k) {
            s_sel[0] = (unsigned int)(2 * tid);
            s_sel[1] = (unsigned int)k - r;
            s_tavg   = s0 / (float)c0;
        }
        scur = r; r -= c1;
        if (scur >= (unsigned int)k && r < (unsigned int)k) {
            s_sel[0] = (unsigned int)(2 * tid + 1);
            s_sel[1] = (unsigned int)k - r;
            s_tavg   = s1 / (float)c1;
        }
        __syncthreads();
        const unsigned int b1 = s_sel[0], remk = s_sel[1];

        float sg = 0.f;
        if ((unsigned int)(2 * tid)     > b1) sg += s0;
        if ((unsigned int)(2 * tid + 1) > b1) sg += s1;
        #pragma unroll
        for (int off = 32; off > 0; off >>= 1) sg += __shfl_xor(sg, off);
        if (lane == 0) s_rf[wave] = sg;
        __syncthreads();
        if (tid == 0) {
            float t = 0.f;
            for (int w = 0; w < 16; ++w) t += s_rf[w];
            sum_sel = t + (float)remk * s_tavg;
        }
    }

    // ---- per-row contribution + last-block final mean ----
    if (tid == 0) {
        float row_lb = g_lb[4*b] + g_lb[4*b+1] + g_lb[4*b+2] + g_lb[4*b+3];
        float row_pb = g_pbce[4*b] + g_pbce[4*b+1] + g_pbce[4*b+2] + g_pbce[4*b+3];
        float nm  = (pn > 0) ? 1.f : 0.f;
        float pcn = fmaxf((float)pn, FLT_EPS_);
        g_rowc[b]          = row_lb * nm / pcn;
        g_rowc[B_ + b]     = (row_pb + sum_sel) * nm / pcn;
        g_rowc[2 * B_ + b] = nm / pcn;
        __threadfence();
        unsigned int old = atomicAdd(g_cnt, 1u);
        s_last = (old == (unsigned int)(B_ - 1)) ? 1 : 0;
    }
    __syncthreads();
    if (s_last && wave == 0) {
        // atomic reads bypass stale L1/L2 lines; fixed tree -> deterministic
        float lb_t = atomicAdd(&g_rowc[lane], 0.f)          + atomicAdd(&g_rowc[lane + 64], 0.f);
        float ll_t = atomicAdd(&g_rowc[B_ + lane], 0.f)     + atomicAdd(&g_rowc[B_ + lane + 64], 0.f);
        float w_t  = atomicAdd(&g_rowc[2 * B_ + lane], 0.f) + atomicAdd(&g_rowc[2 * B_ + lane + 64], 0.f);
        #pragma unroll
        for (int off = 32; off > 0; off >>= 1) {
            lb_t += __shfl_xor(lb_t, off);
            ll_t += __shfl_xor(ll_t, off);
            w_t  += __shfl_xor(w_t, off);
        }
        if (lane == 0) {
            float LB = lb_t * (1.f / B_);
            float LL = ll_t * (1.f / B_);
            float W  = w_t  * (1.f / B_);
            out[0] = (LB + LL) * W;
            out[1] = LB;
            out[2] = LL;
        }
    }
}

extern "C" void kernel_launch(void* const* d_in, const int* in_sizes, int n_in,
                              void* d_out, int out_size, void* d_ws, size_t ws_size,
                              hipStream_t stream) {
    const float* pbboxs  = (const float*)d_in[0];
    const float* plabels = (const float*)d_in[1];
    const float* gbboxs  = (const float*)d_in[2];
    const float* glabels = (const float*)d_in[3];
    const float* ancs    = (const float*)d_in[4];
    float* out = (float*)d_out;

    char* ws = (char*)d_ws;
    unsigned int* g_cnt = (unsigned int*)ws;                        // 4 B (64 B pad)
    unsigned long long* g_h = (unsigned long long*)(ws + 64);       // 8.4 MB
    size_t off = 64 + (size_t)NBLK_A * NBINS * 8;
    float* g_lb   = (float*)(ws + off);  off += NBLK_A * 4;
    float* g_pbce = (float*)(ws + off);  off += NBLK_A * 4;
    int*   g_pn   = (int*)(ws + off);    off += NBLK_A * 4;
    float* g_rowc = (float*)(ws + off);

    // no memset: pass1 zeroes g_cnt; every other workspace word is
    // written before it is read
    pass1_kernel<<<NBLK_A, 1024, 0, stream>>>(
        pbboxs, plabels, gbboxs, glabels, ancs, g_h, g_lb, g_pbce, g_pn, g_cnt);
    select_final_kernel<<<B_, 1024, 0, stream>>>(
        g_h, g_lb, g_pbce, g_pn, g_rowc, g_cnt, out);
}